// Round 1
// 266.982 us; speedup vs baseline: 1.1174x; 1.1174x over previous
//
#include <hip/hip_runtime.h>
#include <math.h>

#define NNODES 50000
#define NEDGES 800000
#define GB 782  // gemm1 row-blocks = (NNODES+63)/64

typedef _Float16 f16;
typedef _Float16 f16x8 __attribute__((ext_vector_type(8)));
typedef _Float16 f16x4 __attribute__((ext_vector_type(4)));
typedef _Float16 f16x2 __attribute__((ext_vector_type(2)));
typedef float f32x4 __attribute__((ext_vector_type(4)));
typedef float f32x8 __attribute__((ext_vector_type(8)));

// ---------------- CSR build + weight pack ----------------

// blocks [0,3125): degree histogram + per-edge rank (atomic return value);
// blocks [3125,3285): weight fragment pack
__global__ __launch_bounds__(256) void k_deg_wfrag(const int* __restrict__ ei, int* __restrict__ deg,
                                                   int* __restrict__ rank,
                                                   const float* __restrict__ W1, const float* __restrict__ W2,
                                                   f16* __restrict__ W1f, f16* __restrict__ W2f) {
    int bid = blockIdx.x;
    if (bid < NEDGES / 256) {
        int e = bid * 256 + threadIdx.x;
        rank[e] = atomicAdd(&deg[ei[NEDGES + e]], 1);
    } else {
        int id = (bid - NEDGES / 256) * 256 + threadIdx.x;
        if (id < 32768) {  // W1: 128 x 256
            int k = id >> 8, c = id & 255;
            int kc = k >> 5, quad = (k & 31) >> 3, j = k & 7;
            W1f[(((kc << 8) + c) * 4 + quad) * 8 + j] = (f16)W1[id];
        } else {           // W2: 256 x 32
            int i2 = id - 32768;
            int k = i2 >> 5, c = i2 & 31;
            int kc = k >> 5, quad = (k & 31) >> 3, j = k & 7;
            W2f[(((kc << 5) + c) * 4 + quad) * 8 + j] = (f16)W2[i2];
        }
    }
}

__global__ __launch_bounds__(256) void k_scanA(const int* __restrict__ deg, int* __restrict__ incl,
                                               int* __restrict__ partial) {
    int t = threadIdx.x;
    int i = blockIdx.x * 256 + t;
    int v = (i < NNODES) ? deg[i] : 0;
    int lane = t & 63, wid = t >> 6;
    int s = v;
#pragma unroll
    for (int d = 1; d < 64; d <<= 1) { int u = __shfl_up(s, d, 64); if (lane >= d) s += u; }
    __shared__ int wtot[4];
    if (lane == 63) wtot[wid] = s;
    __syncthreads();
    int off = 0;
    for (int w = 0; w < wid; ++w) off += wtot[w];
    s += off;
    if (i < NNODES) incl[i] = s;
    if (t == 255) partial[blockIdx.x] = s;
}

__global__ __launch_bounds__(256) void k_scanC(const int* __restrict__ deg, const int* __restrict__ incl,
                                               const int* __restrict__ partial, int* __restrict__ rowst) {
    int t = threadIdx.x, bid = blockIdx.x;
    int v = (t < bid) ? partial[t] : 0;  // bid <= 195 < 256
    int lane = t & 63, wid = t >> 6;
#pragma unroll
    for (int d = 1; d < 64; d <<= 1) v += __shfl_xor(v, d);
    __shared__ int ws[4];
    if (lane == 0) ws[wid] = v;
    __syncthreads();
    int choff = ws[0] + ws[1] + ws[2] + ws[3];
    int i = bid * 256 + t;
    if (i < NNODES) {
        int rs1 = incl[i] + choff;
        rowst[i + 1] = rs1;
        if (i == 0) rowst[0] = 0;
    }
}

// ---------------- gemm1 + atomic-free thin scatter (merged grid) ----------------
// mfma_f32_16x16x32_f16 (lane=tid&63, r=lane&15, quad=lane>>4):
//   A frag a[j]=A[r][quad*8+j]  B frag b[j]=B[quad*8+j][r]  D d[i]=D[quad*4+i][r]
// Blocks [0,GB): h1h = X @ W1 (64 rows x 256 cols) + fused alpha dots.
// Blocks [GB,GB+3125): scatter sd_csr[rowst[d]+rank[e]] = (d<<16)|s — no atomic,
// fire-and-forget stores pipeline at throughput; overlaps the MFMA blocks.

__global__ __launch_bounds__(256) void k_gemm1_sc(const float* __restrict__ X, const f16* __restrict__ W1f,
                                                  const float* __restrict__ Asrc, const float* __restrict__ Adst,
                                                  f16* __restrict__ h1h, float* __restrict__ as1,
                                                  float* __restrict__ ad1, const int* __restrict__ ei,
                                                  const int* __restrict__ rowst, const int* __restrict__ rank,
                                                  unsigned* __restrict__ sd_csr) {
    __shared__ f16 sA[64 * 136];
    int bid = blockIdx.x;
    int t = threadIdx.x;
    if (bid >= GB) {  // scatter path (uniform per block)
        int e = (bid - GB) * 256 + t;
        if (e < NEDGES) {
            int s = ei[e], d = ei[NEDGES + e];
            int pos = rowst[d] + rank[e];
            sd_csr[pos] = ((unsigned)d << 16) | (unsigned)s;
        }
        return;
    }
    int bm = bid * 64;
#pragma unroll
    for (int i = 0; i < 8; ++i) {
        int idx = i * 256 + t;
        int row = idx >> 5, c4 = (idx & 31) << 2;
        int gr = bm + row;
        float4 v = make_float4(0.f, 0.f, 0.f, 0.f);
        if (gr < NNODES) v = *(const float4*)(X + (size_t)gr * 128 + c4);
        f16x4 h = {(f16)v.x, (f16)v.y, (f16)v.z, (f16)v.w};
        *(f16x4*)&sA[row * 136 + c4] = h;
    }
    __syncthreads();
    int lane = t & 63, w = t >> 6;
    int r = lane & 15, quad = lane >> 4;
    int r0 = w * 16;
    f32x4 acc[2][8];
#pragma unroll
    for (int h2 = 0; h2 < 2; ++h2)
#pragma unroll
        for (int nt = 0; nt < 8; ++nt) acc[h2][nt] = (f32x4){0.f, 0.f, 0.f, 0.f};
#pragma unroll
    for (int kc = 0; kc < 4; ++kc) {
        f16x8 a = *(f16x8*)&sA[(r0 + r) * 136 + kc * 32 + quad * 8];
#pragma unroll
        for (int h2 = 0; h2 < 2; ++h2)
#pragma unroll
            for (int nt = 0; nt < 8; ++nt) {
                f16x8 b = *(const f16x8*)&W1f[(((kc << 8) + h2 * 128 + nt * 16 + r) * 4 + quad) * 8];
                acc[h2][nt] = __builtin_amdgcn_mfma_f32_16x16x32_f16(a, b, acc[h2][nt], 0, 0, 0);
            }
    }
#pragma unroll
    for (int h2 = 0; h2 < 2; ++h2)
#pragma unroll
        for (int nt = 0; nt < 8; ++nt)
#pragma unroll
            for (int i = 0; i < 4; ++i) {
                int gr = bm + r0 + quad * 4 + i;
                if (gr < NNODES) h1h[(size_t)gr * 256 + h2 * 128 + nt * 16 + r] = (f16)acc[h2][nt][i];
            }
    // fused alpha for all 8 heads (head = h2*4 + hl)
#pragma unroll
    for (int h2 = 0; h2 < 2; ++h2) {
        float asv[8], adv[8];
#pragma unroll
        for (int nt = 0; nt < 8; ++nt) {
            asv[nt] = Asrc[h2 * 128 + nt * 16 + r];
            adv[nt] = Adst[h2 * 128 + nt * 16 + r];
        }
#pragma unroll
        for (int i = 0; i < 4; ++i) {
            int gr = bm + r0 + quad * 4 + i;
#pragma unroll
            for (int hl = 0; hl < 4; ++hl) {
                float ps = acc[h2][2 * hl][i] * asv[2 * hl] + acc[h2][2 * hl + 1][i] * asv[2 * hl + 1];
                float pd = acc[h2][2 * hl][i] * adv[2 * hl] + acc[h2][2 * hl + 1][i] * adv[2 * hl + 1];
#pragma unroll
                for (int off = 1; off < 16; off <<= 1) {
                    ps += __shfl_xor(ps, off);
                    pd += __shfl_xor(pd, off);
                }
                if (r == 0 && gr < NNODES) {
                    as1[(size_t)gr * 8 + h2 * 4 + hl] = ps;
                    ad1[(size_t)gr * 8 + h2 * 4 + hl] = pd;
                }
            }
        }
    }
}

// gh[N,32](f16) = h2h @ W2; 64 rows per block; no LDS. Fused: layer-2 alpha dots.
__global__ __launch_bounds__(256) void k_gemm2(const f16* __restrict__ h2h, const f16* __restrict__ W2f,
                                               const float* __restrict__ Asrc, const float* __restrict__ Adst,
                                               f16* __restrict__ gh, float* __restrict__ as2,
                                               float* __restrict__ ad2) {
    int t = threadIdx.x;
    int bm = blockIdx.x * 64;
    int lane = t & 63, w = t >> 6;
    int r = lane & 15, quad = lane >> 4;
    int r0 = w * 16;
    int gra = bm + r0 + r;
    int grac = gra < NNODES ? gra : 0;
    f32x4 acc[2];
    acc[0] = (f32x4){0.f, 0.f, 0.f, 0.f};
    acc[1] = (f32x4){0.f, 0.f, 0.f, 0.f};
#pragma unroll
    for (int kc = 0; kc < 8; ++kc) {
        f16x8 a = *(const f16x8*)(h2h + (size_t)grac * 256 + kc * 32 + quad * 8);
#pragma unroll
        for (int nt = 0; nt < 2; ++nt) {
            f16x8 b = *(const f16x8*)&W2f[(((kc << 5) + nt * 16 + r) * 4 + quad) * 8];
            acc[nt] = __builtin_amdgcn_mfma_f32_16x16x32_f16(a, b, acc[nt], 0, 0, 0);
        }
    }
#pragma unroll
    for (int nt = 0; nt < 2; ++nt)
#pragma unroll
        for (int i = 0; i < 4; ++i) {
            int gr = bm + r0 + quad * 4 + i;
            if (gr < NNODES) gh[(size_t)gr * 32 + nt * 16 + r] = (f16)acc[nt][i];
        }
    float as0 = Asrc[r], as16 = Asrc[16 + r];
    float ad0 = Adst[r], ad16 = Adst[16 + r];
#pragma unroll
    for (int i = 0; i < 4; ++i) {
        int gr = bm + r0 + quad * 4 + i;
        float ps = acc[0][i] * as0 + acc[1][i] * as16;
        float pd = acc[0][i] * ad0 + acc[1][i] * ad16;
#pragma unroll
        for (int off = 1; off < 16; off <<= 1) {
            ps += __shfl_xor(ps, off);
            pd += __shfl_xor(pd, off);
        }
        if (r == 0 && gr < NNODES) { as2[gr] = ps; ad2[gr] = pd; }
    }
}

// ---------------- fused softmax + aggregate ----------------
// No max-subtraction: logits O(1) by construction (validated R6-R15).
// SINGLE PASS: accumulate un-normalized numerator acc[c] = sum_e exp(x_e)*h1[src_e][c]
// and denominator sum = sum_e exp(x_e) in the same loop; scale by 1/sum at the end.
// Removes the eh round-trip (25.6 MB traffic) and the stats->waitcnt->main
// serialization that exposed two gather-latency chains per wave.

// Wave-per-node, 4 nodes/block. lane = slot(2) x ch32; each lane covers 8 channels
// (f16x8 gather, 16 B/lane) of head hm = ch32>>2; alpha recomputed per edge from
// L2-resident as1 (1.6 MB).
__global__ __launch_bounds__(256) void k_agg1(const int* __restrict__ rowst, const unsigned* __restrict__ sd_csr,
                                              const float* __restrict__ as1, const float* __restrict__ ad1,
                                              const f16* __restrict__ h1h, const float* __restrict__ b1,
                                              f16* __restrict__ h2h) {
    int w = threadIdx.x >> 6, lane = threadIdx.x & 63;
    int n = blockIdx.x * 4 + w;
    int s = rowst[n], e = rowst[n + 1];
    int slot = lane >> 5;
    int ch32 = lane & 31;
    int c0 = ch32 << 3;
    int hm = ch32 >> 2;
    float adn = ad1[(size_t)n * 8 + hm];
    const f16* __restrict__ hp = h1h + c0;
    const float* __restrict__ ap = as1 + hm;
    f32x8 acc = (f32x8){0.f, 0.f, 0.f, 0.f, 0.f, 0.f, 0.f, 0.f};
    float sum = 0.f;
    int j = s + slot;
    for (; j + 6 < e; j += 8) {
        int s0 = (int)(sd_csr[j] & 0xffffu),     s1 = (int)(sd_csr[j + 2] & 0xffffu);
        int s2 = (int)(sd_csr[j + 4] & 0xffffu), s3 = (int)(sd_csr[j + 6] & 0xffffu);
        float x0 = ap[(size_t)s0 * 8] + adn;
        float x1 = ap[(size_t)s1 * 8] + adn;
        float x2 = ap[(size_t)s2 * 8] + adn;
        float x3 = ap[(size_t)s3 * 8] + adn;
        f16x8 v0 = *(const f16x8*)(hp + (size_t)s0 * 256);
        f16x8 v1 = *(const f16x8*)(hp + (size_t)s1 * 256);
        f16x8 v2 = *(const f16x8*)(hp + (size_t)s2 * 256);
        f16x8 v3 = *(const f16x8*)(hp + (size_t)s3 * 256);
        x0 = fmaxf(x0, 0.2f * x0);
        x1 = fmaxf(x1, 0.2f * x1);
        x2 = fmaxf(x2, 0.2f * x2);
        x3 = fmaxf(x3, 0.2f * x3);
        float e0 = __expf(x0), e1 = __expf(x1), e2 = __expf(x2), e3 = __expf(x3);
        sum += (e0 + e1) + (e2 + e3);
#pragma unroll
        for (int k = 0; k < 8; ++k)
            acc[k] += e0 * (float)v0[k] + e1 * (float)v1[k] + e2 * (float)v2[k] + e3 * (float)v3[k];
    }
    for (; j < e; j += 2) {
        int s0 = (int)(sd_csr[j] & 0xffffu);
        float x0 = ap[(size_t)s0 * 8] + adn;
        f16x8 v0 = *(const f16x8*)(hp + (size_t)s0 * 256);
        x0 = fmaxf(x0, 0.2f * x0);
        float e0 = __expf(x0);
        sum += e0;
#pragma unroll
        for (int k = 0; k < 8; ++k) acc[k] += e0 * (float)v0[k];
    }
    sum += __shfl_xor(sum, 32);
#pragma unroll
    for (int k = 0; k < 8; ++k) acc[k] += __shfl_xor(acc[k], 32);
    if (slot == 0) {
        float inv = 1.f / (sum + 1e-16f);
        float4 b0 = *(const float4*)(b1 + c0);
        float4 b4 = *(const float4*)(b1 + c0 + 4);
        float o[8] = {acc[0] * inv + b0.x, acc[1] * inv + b0.y, acc[2] * inv + b0.z, acc[3] * inv + b0.w,
                      acc[4] * inv + b4.x, acc[5] * inv + b4.y, acc[6] * inv + b4.z, acc[7] * inv + b4.w};
        f16x8 oh;
#pragma unroll
        for (int k = 0; k < 8; ++k) {
            float v = o[k];
            v = v > 0.f ? v : __expf(v) - 1.f;  // fused ELU
            oh[k] = (f16)v;
        }
        *(f16x8*)(h2h + (size_t)n * 256 + c0) = oh;
    }
}

// Wave-per-node, single pass; lane = slot(4) x chpair(16), f16x2 gathers of gh
// (3.2 MB, effectively L2-resident); alpha from L2-resident as2 (200 KB).
__global__ __launch_bounds__(256) void k_agg2(const int* __restrict__ rowst, const unsigned* __restrict__ sd_csr,
                                              const float* __restrict__ as2, const float* __restrict__ ad2,
                                              const f16* __restrict__ gh, const float* __restrict__ b2,
                                              float* __restrict__ out) {
    int w = threadIdx.x >> 6, lane = threadIdx.x & 63;
    int n = blockIdx.x * 4 + w;
    int s = rowst[n], e = rowst[n + 1];
    int slot = lane >> 4;
    int cp = lane & 15;  // channels 2cp, 2cp+1
    float adn = ad2[n];
    const f16* __restrict__ gp = gh + 2 * cp;
    float a0 = 0.f, a1 = 0.f, sum = 0.f;
    int j = s + slot;
    for (; j + 4 < e; j += 8) {
        int s0 = (int)(sd_csr[j] & 0xffffu);
        int s1 = (int)(sd_csr[j + 4] & 0xffffu);
        float x0 = as2[s0] + adn, x1 = as2[s1] + adn;
        f16x2 v0 = *(const f16x2*)(gp + (size_t)s0 * 32);
        f16x2 v1 = *(const f16x2*)(gp + (size_t)s1 * 32);
        x0 = fmaxf(x0, 0.2f * x0);
        x1 = fmaxf(x1, 0.2f * x1);
        float e0 = __expf(x0), e1 = __expf(x1);
        sum += e0 + e1;
        a0 += e0 * (float)v0[0] + e1 * (float)v1[0];
        a1 += e0 * (float)v0[1] + e1 * (float)v1[1];
    }
    for (; j < e; j += 4) {
        int s0 = (int)(sd_csr[j] & 0xffffu);
        float x0 = as2[s0] + adn;
        f16x2 v0 = *(const f16x2*)(gp + (size_t)s0 * 32);
        x0 = fmaxf(x0, 0.2f * x0);
        float e0 = __expf(x0);
        sum += e0;
        a0 += e0 * (float)v0[0];
        a1 += e0 * (float)v0[1];
    }
#pragma unroll
    for (int d = 16; d < 64; d <<= 1) {
        sum += __shfl_xor(sum, d);
        a0 += __shfl_xor(a0, d);
        a1 += __shfl_xor(a1, d);
    }
    if (slot == 0) {
        float inv = 1.f / (sum + 1e-16f);
        float2 o;
        o.x = a0 * inv + b2[2 * cp];
        o.y = a1 * inv + b2[2 * cp + 1];
        *(float2*)(out + (size_t)n * 32 + 2 * cp) = o;
    }
}

// ---------------- launch ----------------

extern "C" void kernel_launch(void* const* d_in, const int* in_sizes, int n_in,
                              void* d_out, int out_size, void* d_ws, size_t ws_size,
                              hipStream_t stream) {
    const float* x    = (const float*)d_in[0];
    const int*   ei   = (const int*)d_in[1];
    const float* W1   = (const float*)d_in[2];
    const float* As1  = (const float*)d_in[3];
    const float* Ad1  = (const float*)d_in[4];
    const float* b1   = (const float*)d_in[5];
    const float* W2   = (const float*)d_in[6];
    const float* As2  = (const float*)d_in[7];
    const float* Ad2  = (const float*)d_in[8];
    const float* b2   = (const float*)d_in[9];
    float* out = (float*)d_out;

    char* p = (char*)d_ws;
    auto alloc = [&](size_t bytes) -> char* {
        char* r = p;
        p += (bytes + 255) & ~(size_t)255;
        return r;
    };
    f16* h1h      = (f16*)alloc((size_t)NNODES * 256 * 2);
    f16* h2h      = (f16*)alloc((size_t)NNODES * 256 * 2);
    f16* W1f      = (f16*)alloc((size_t)128 * 256 * 2);
    f16* W2f      = (f16*)alloc((size_t)256 * 32 * 2);
    f16* gh       = (f16*)alloc((size_t)NNODES * 32 * 2);
    float* asrc1  = (float*)alloc((size_t)NNODES * 8 * 4);
    float* adst1  = (float*)alloc((size_t)NNODES * 8 * 4);
    float* asrc2  = (float*)alloc((size_t)NNODES * 4);
    float* adst2  = (float*)alloc((size_t)NNODES * 4);
    int* deg      = (int*)alloc((size_t)NNODES * 4);
    int* incl     = (int*)alloc((size_t)NNODES * 4);
    int* rowst    = (int*)alloc((size_t)(NNODES + 1) * 4);
    int* rank     = (int*)alloc((size_t)NEDGES * 4);
    unsigned* sdc = (unsigned*)alloc((size_t)NEDGES * 4);
    int* partial  = (int*)alloc(256 * 4);

    const int EB = NEDGES / 256;           // 3125
    const int NCH = (NNODES + 255) / 256;  // 196

    hipMemsetAsync(deg, 0, (size_t)NNODES * 4, stream);
    k_deg_wfrag<<<EB + 160, 256, 0, stream>>>(ei, deg, rank, W1, W2, W1f, W2f);
    k_scanA<<<NCH, 256, 0, stream>>>(deg, incl, partial);
    k_scanC<<<NCH, 256, 0, stream>>>(deg, incl, partial, rowst);

    k_gemm1_sc<<<GB + EB, 256, 0, stream>>>(x, W1f, As1, Ad1, h1h, asrc1, adst1, ei, rowst, rank, sdc);
    k_agg1<<<NNODES / 4, 256, 0, stream>>>(rowst, sdc, asrc1, adst1, h1h, b1, h2h);

    k_gemm2<<<(NNODES + 63) / 64, 256, 0, stream>>>(h2h, W2f, As2, Ad2, gh, asrc2, adst2);
    k_agg2<<<NNODES / 4, 256, 0, stream>>>(rowst, sdc, asrc2, adst2, gh, b2, out);
}

// Round 2
// 265.849 us; speedup vs baseline: 1.1222x; 1.0043x over previous
//
#include <hip/hip_runtime.h>
#include <math.h>

#define NNODES 50000
#define NEDGES 800000
#define GB 782  // gemm1 row-blocks = (NNODES+63)/64

typedef _Float16 f16;
typedef _Float16 f16x8 __attribute__((ext_vector_type(8)));
typedef _Float16 f16x4 __attribute__((ext_vector_type(4)));
typedef _Float16 f16x2 __attribute__((ext_vector_type(2)));
typedef float f32x4 __attribute__((ext_vector_type(4)));
typedef float f32x8 __attribute__((ext_vector_type(8)));

// ---------------- CSR build + weight pack ----------------

// blocks [0,3125): degree histogram + per-edge rank (atomic return value);
// blocks [3125,3285): weight fragment pack
__global__ __launch_bounds__(256) void k_deg_wfrag(const int* __restrict__ ei, int* __restrict__ deg,
                                                   int* __restrict__ rank,
                                                   const float* __restrict__ W1, const float* __restrict__ W2,
                                                   f16* __restrict__ W1f, f16* __restrict__ W2f) {
    int bid = blockIdx.x;
    if (bid < NEDGES / 256) {
        int e = bid * 256 + threadIdx.x;
        rank[e] = atomicAdd(&deg[ei[NEDGES + e]], 1);
    } else {
        int id = (bid - NEDGES / 256) * 256 + threadIdx.x;
        if (id < 32768) {  // W1: 128 x 256
            int k = id >> 8, c = id & 255;
            int kc = k >> 5, quad = (k & 31) >> 3, j = k & 7;
            W1f[(((kc << 8) + c) * 4 + quad) * 8 + j] = (f16)W1[id];
        } else {           // W2: 256 x 32
            int i2 = id - 32768;
            int k = i2 >> 5, c = i2 & 31;
            int kc = k >> 5, quad = (k & 31) >> 3, j = k & 7;
            W2f[(((kc << 5) + c) * 4 + quad) * 8 + j] = (f16)W2[i2];
        }
    }
}

__global__ __launch_bounds__(256) void k_scanA(const int* __restrict__ deg, int* __restrict__ incl,
                                               int* __restrict__ partial) {
    int t = threadIdx.x;
    int i = blockIdx.x * 256 + t;
    int v = (i < NNODES) ? deg[i] : 0;
    int lane = t & 63, wid = t >> 6;
    int s = v;
#pragma unroll
    for (int d = 1; d < 64; d <<= 1) { int u = __shfl_up(s, d, 64); if (lane >= d) s += u; }
    __shared__ int wtot[4];
    if (lane == 63) wtot[wid] = s;
    __syncthreads();
    int off = 0;
    for (int w = 0; w < wid; ++w) off += wtot[w];
    s += off;
    if (i < NNODES) incl[i] = s;
    if (t == 255) partial[blockIdx.x] = s;
}

__global__ __launch_bounds__(256) void k_scanC(const int* __restrict__ deg, const int* __restrict__ incl,
                                               const int* __restrict__ partial, int* __restrict__ rowst) {
    int t = threadIdx.x, bid = blockIdx.x;
    int v = (t < bid) ? partial[t] : 0;  // bid <= 195 < 256
    int lane = t & 63, wid = t >> 6;
#pragma unroll
    for (int d = 1; d < 64; d <<= 1) v += __shfl_xor(v, d);
    __shared__ int ws[4];
    if (lane == 0) ws[wid] = v;
    __syncthreads();
    int choff = ws[0] + ws[1] + ws[2] + ws[3];
    int i = bid * 256 + t;
    if (i < NNODES) {
        int rs1 = incl[i] + choff;
        rowst[i + 1] = rs1;
        if (i == 0) rowst[0] = 0;
    }
}

// ---------------- gemm1 + atomic-free thin scatter (merged grid) ----------------
// mfma_f32_16x16x32_f16 (lane=tid&63, r=lane&15, quad=lane>>4):
//   A frag a[j]=A[r][quad*8+j]  B frag b[j]=B[quad*8+j][r]  D d[i]=D[quad*4+i][r]
// Blocks [0,GB): h1h = X @ W1 (64 rows x 256 cols) + fused alpha dots.
// Blocks [GB,GB+3125): scatter sd_csr[rowst[d]+rank[e]] = (d<<16)|s — no atomic,
// fire-and-forget stores pipeline at throughput; overlaps the MFMA blocks.

__global__ __launch_bounds__(256) void k_gemm1_sc(const float* __restrict__ X, const f16* __restrict__ W1f,
                                                  const float* __restrict__ Asrc, const float* __restrict__ Adst,
                                                  f16* __restrict__ h1h, float* __restrict__ as1,
                                                  float* __restrict__ ad1, const int* __restrict__ ei,
                                                  const int* __restrict__ rowst, const int* __restrict__ rank,
                                                  unsigned* __restrict__ sd_csr) {
    __shared__ f16 sA[64 * 136];
    int bid = blockIdx.x;
    int t = threadIdx.x;
    if (bid >= GB) {  // scatter path (uniform per block)
        int e = (bid - GB) * 256 + t;
        if (e < NEDGES) {
            int s = ei[e], d = ei[NEDGES + e];
            int pos = rowst[d] + rank[e];
            sd_csr[pos] = ((unsigned)d << 16) | (unsigned)s;
        }
        return;
    }
    int bm = bid * 64;
#pragma unroll
    for (int i = 0; i < 8; ++i) {
        int idx = i * 256 + t;
        int row = idx >> 5, c4 = (idx & 31) << 2;
        int gr = bm + row;
        float4 v = make_float4(0.f, 0.f, 0.f, 0.f);
        if (gr < NNODES) v = *(const float4*)(X + (size_t)gr * 128 + c4);
        f16x4 h = {(f16)v.x, (f16)v.y, (f16)v.z, (f16)v.w};
        *(f16x4*)&sA[row * 136 + c4] = h;
    }
    __syncthreads();
    int lane = t & 63, w = t >> 6;
    int r = lane & 15, quad = lane >> 4;
    int r0 = w * 16;
    f32x4 acc[2][8];
#pragma unroll
    for (int h2 = 0; h2 < 2; ++h2)
#pragma unroll
        for (int nt = 0; nt < 8; ++nt) acc[h2][nt] = (f32x4){0.f, 0.f, 0.f, 0.f};
#pragma unroll
    for (int kc = 0; kc < 4; ++kc) {
        f16x8 a = *(f16x8*)&sA[(r0 + r) * 136 + kc * 32 + quad * 8];
#pragma unroll
        for (int h2 = 0; h2 < 2; ++h2)
#pragma unroll
            for (int nt = 0; nt < 8; ++nt) {
                f16x8 b = *(const f16x8*)&W1f[(((kc << 8) + h2 * 128 + nt * 16 + r) * 4 + quad) * 8];
                acc[h2][nt] = __builtin_amdgcn_mfma_f32_16x16x32_f16(a, b, acc[h2][nt], 0, 0, 0);
            }
    }
#pragma unroll
    for (int h2 = 0; h2 < 2; ++h2)
#pragma unroll
        for (int nt = 0; nt < 8; ++nt)
#pragma unroll
            for (int i = 0; i < 4; ++i) {
                int gr = bm + r0 + quad * 4 + i;
                if (gr < NNODES) h1h[(size_t)gr * 256 + h2 * 128 + nt * 16 + r] = (f16)acc[h2][nt][i];
            }
    // fused alpha for all 8 heads (head = h2*4 + hl)
#pragma unroll
    for (int h2 = 0; h2 < 2; ++h2) {
        float asv[8], adv[8];
#pragma unroll
        for (int nt = 0; nt < 8; ++nt) {
            asv[nt] = Asrc[h2 * 128 + nt * 16 + r];
            adv[nt] = Adst[h2 * 128 + nt * 16 + r];
        }
#pragma unroll
        for (int i = 0; i < 4; ++i) {
            int gr = bm + r0 + quad * 4 + i;
#pragma unroll
            for (int hl = 0; hl < 4; ++hl) {
                float ps = acc[h2][2 * hl][i] * asv[2 * hl] + acc[h2][2 * hl + 1][i] * asv[2 * hl + 1];
                float pd = acc[h2][2 * hl][i] * adv[2 * hl] + acc[h2][2 * hl + 1][i] * adv[2 * hl + 1];
#pragma unroll
                for (int off = 1; off < 16; off <<= 1) {
                    ps += __shfl_xor(ps, off);
                    pd += __shfl_xor(pd, off);
                }
                if (r == 0 && gr < NNODES) {
                    as1[(size_t)gr * 8 + h2 * 4 + hl] = ps;
                    ad1[(size_t)gr * 8 + h2 * 4 + hl] = pd;
                }
            }
        }
    }
}

// gh[N,32](f16) = h2h @ W2; 64 rows per block; no LDS. Fused: layer-2 alpha dots.
__global__ __launch_bounds__(256) void k_gemm2(const f16* __restrict__ h2h, const f16* __restrict__ W2f,
                                               const float* __restrict__ Asrc, const float* __restrict__ Adst,
                                               f16* __restrict__ gh, float* __restrict__ as2,
                                               float* __restrict__ ad2) {
    int t = threadIdx.x;
    int bm = blockIdx.x * 64;
    int lane = t & 63, w = t >> 6;
    int r = lane & 15, quad = lane >> 4;
    int r0 = w * 16;
    int gra = bm + r0 + r;
    int grac = gra < NNODES ? gra : 0;
    f32x4 acc[2];
    acc[0] = (f32x4){0.f, 0.f, 0.f, 0.f};
    acc[1] = (f32x4){0.f, 0.f, 0.f, 0.f};
#pragma unroll
    for (int kc = 0; kc < 8; ++kc) {
        f16x8 a = *(const f16x8*)(h2h + (size_t)grac * 256 + kc * 32 + quad * 8);
#pragma unroll
        for (int nt = 0; nt < 2; ++nt) {
            f16x8 b = *(const f16x8*)&W2f[(((kc << 5) + nt * 16 + r) * 4 + quad) * 8];
            acc[nt] = __builtin_amdgcn_mfma_f32_16x16x32_f16(a, b, acc[nt], 0, 0, 0);
        }
    }
#pragma unroll
    for (int nt = 0; nt < 2; ++nt)
#pragma unroll
        for (int i = 0; i < 4; ++i) {
            int gr = bm + r0 + quad * 4 + i;
            if (gr < NNODES) gh[(size_t)gr * 32 + nt * 16 + r] = (f16)acc[nt][i];
        }
    float as0 = Asrc[r], as16 = Asrc[16 + r];
    float ad0 = Adst[r], ad16 = Adst[16 + r];
#pragma unroll
    for (int i = 0; i < 4; ++i) {
        int gr = bm + r0 + quad * 4 + i;
        float ps = acc[0][i] * as0 + acc[1][i] * as16;
        float pd = acc[0][i] * ad0 + acc[1][i] * ad16;
#pragma unroll
        for (int off = 1; off < 16; off <<= 1) {
            ps += __shfl_xor(ps, off);
            pd += __shfl_xor(pd, off);
        }
        if (r == 0 && gr < NNODES) { as2[gr] = ps; ad2[gr] = pd; }
    }
}

// ---------------- fused softmax + aggregate ----------------
// No max-subtraction: logits O(1) by construction (validated R6-R15).
// Single pass (R0->R1: -13us). R1->R2: latency-bound (no pipe >50%) -> deepen
// MLP: 8-edge unroll per slot, all indices -> all alphas -> all rows issued
// before any arithmetic; unroll-4 and unroll-2 tails for low-degree nodes.

// Wave-per-node, 4 nodes/block. lane = slot(2) x ch32; each lane covers 8 channels
// (f16x8 gather, 16 B/lane) of head hm = ch32>>2; alpha recomputed per edge from
// L2-resident as1 (1.6 MB).
__global__ __launch_bounds__(256) void k_agg1(const int* __restrict__ rowst, const unsigned* __restrict__ sd_csr,
                                              const float* __restrict__ as1, const float* __restrict__ ad1,
                                              const f16* __restrict__ h1h, const float* __restrict__ b1,
                                              f16* __restrict__ h2h) {
    int w = threadIdx.x >> 6, lane = threadIdx.x & 63;
    int n = blockIdx.x * 4 + w;
    int s = rowst[n], e = rowst[n + 1];
    int slot = lane >> 5;
    int ch32 = lane & 31;
    int c0 = ch32 << 3;
    int hm = ch32 >> 2;
    float adn = ad1[(size_t)n * 8 + hm];
    const f16* __restrict__ hp = h1h + c0;
    const float* __restrict__ ap = as1 + hm;
    f32x8 acc = (f32x8){0.f, 0.f, 0.f, 0.f, 0.f, 0.f, 0.f, 0.f};
    float sum = 0.f;
    int j = s + slot;
    // 8-edge unroll: 8 index loads, 8 alpha gathers, 8 f16x8 row gathers in flight
    for (; j + 14 < e; j += 16) {
        int si[8];
#pragma unroll
        for (int u = 0; u < 8; ++u) si[u] = (int)(sd_csr[j + 2 * u] & 0xffffu);
        float xv[8];
#pragma unroll
        for (int u = 0; u < 8; ++u) xv[u] = ap[(size_t)si[u] * 8];
        f16x8 vv[8];
#pragma unroll
        for (int u = 0; u < 8; ++u) vv[u] = *(const f16x8*)(hp + (size_t)si[u] * 256);
#pragma unroll
        for (int u = 0; u < 8; ++u) {
            float x = xv[u] + adn;
            x = fmaxf(x, 0.2f * x);
            float ee = __expf(x);
            sum += ee;
#pragma unroll
            for (int k = 0; k < 8; ++k) acc[k] += ee * (float)vv[u][k];
        }
    }
    // 4-edge tail
    for (; j + 6 < e; j += 8) {
        int si[4];
#pragma unroll
        for (int u = 0; u < 4; ++u) si[u] = (int)(sd_csr[j + 2 * u] & 0xffffu);
        float xv[4];
#pragma unroll
        for (int u = 0; u < 4; ++u) xv[u] = ap[(size_t)si[u] * 8];
        f16x8 vv[4];
#pragma unroll
        for (int u = 0; u < 4; ++u) vv[u] = *(const f16x8*)(hp + (size_t)si[u] * 256);
#pragma unroll
        for (int u = 0; u < 4; ++u) {
            float x = xv[u] + adn;
            x = fmaxf(x, 0.2f * x);
            float ee = __expf(x);
            sum += ee;
#pragma unroll
            for (int k = 0; k < 8; ++k) acc[k] += ee * (float)vv[u][k];
        }
    }
    // 1-edge tail
    for (; j < e; j += 2) {
        int s0 = (int)(sd_csr[j] & 0xffffu);
        float x0 = ap[(size_t)s0 * 8] + adn;
        f16x8 v0 = *(const f16x8*)(hp + (size_t)s0 * 256);
        x0 = fmaxf(x0, 0.2f * x0);
        float e0 = __expf(x0);
        sum += e0;
#pragma unroll
        for (int k = 0; k < 8; ++k) acc[k] += e0 * (float)v0[k];
    }
    sum += __shfl_xor(sum, 32);
#pragma unroll
    for (int k = 0; k < 8; ++k) acc[k] += __shfl_xor(acc[k], 32);
    if (slot == 0) {
        float inv = 1.f / (sum + 1e-16f);
        float4 b0 = *(const float4*)(b1 + c0);
        float4 b4 = *(const float4*)(b1 + c0 + 4);
        float o[8] = {acc[0] * inv + b0.x, acc[1] * inv + b0.y, acc[2] * inv + b0.z, acc[3] * inv + b0.w,
                      acc[4] * inv + b4.x, acc[5] * inv + b4.y, acc[6] * inv + b4.z, acc[7] * inv + b4.w};
        f16x8 oh;
#pragma unroll
        for (int k = 0; k < 8; ++k) {
            float v = o[k];
            v = v > 0.f ? v : __expf(v) - 1.f;  // fused ELU
            oh[k] = (f16)v;
        }
        *(f16x8*)(h2h + (size_t)n * 256 + c0) = oh;
    }
}

// Wave-per-node, single pass; lane = slot(4) x chpair(16), f16x2 gathers of gh
// (3.2 MB, effectively L2-resident); alpha from L2-resident as2 (200 KB).
// 4-edge unroll per slot for MLP depth, then 2-edge, then 1-edge tails.
__global__ __launch_bounds__(256) void k_agg2(const int* __restrict__ rowst, const unsigned* __restrict__ sd_csr,
                                              const float* __restrict__ as2, const float* __restrict__ ad2,
                                              const f16* __restrict__ gh, const float* __restrict__ b2,
                                              float* __restrict__ out) {
    int w = threadIdx.x >> 6, lane = threadIdx.x & 63;
    int n = blockIdx.x * 4 + w;
    int s = rowst[n], e = rowst[n + 1];
    int slot = lane >> 4;
    int cp = lane & 15;  // channels 2cp, 2cp+1
    float adn = ad2[n];
    const f16* __restrict__ gp = gh + 2 * cp;
    float a0 = 0.f, a1 = 0.f, sum = 0.f;
    int j = s + slot;
    // 4-edge unroll
    for (; j + 12 < e; j += 16) {
        int si[4];
#pragma unroll
        for (int u = 0; u < 4; ++u) si[u] = (int)(sd_csr[j + 4 * u] & 0xffffu);
        float xv[4];
#pragma unroll
        for (int u = 0; u < 4; ++u) xv[u] = as2[si[u]];
        f16x2 vv[4];
#pragma unroll
        for (int u = 0; u < 4; ++u) vv[u] = *(const f16x2*)(gp + (size_t)si[u] * 32);
#pragma unroll
        for (int u = 0; u < 4; ++u) {
            float x = xv[u] + adn;
            x = fmaxf(x, 0.2f * x);
            float ee = __expf(x);
            sum += ee;
            a0 += ee * (float)vv[u][0];
            a1 += ee * (float)vv[u][1];
        }
    }
    // 2-edge tail
    for (; j + 4 < e; j += 8) {
        int s0 = (int)(sd_csr[j] & 0xffffu);
        int s1 = (int)(sd_csr[j + 4] & 0xffffu);
        float x0 = as2[s0] + adn, x1 = as2[s1] + adn;
        f16x2 v0 = *(const f16x2*)(gp + (size_t)s0 * 32);
        f16x2 v1 = *(const f16x2*)(gp + (size_t)s1 * 32);
        x0 = fmaxf(x0, 0.2f * x0);
        x1 = fmaxf(x1, 0.2f * x1);
        float e0 = __expf(x0), e1 = __expf(x1);
        sum += e0 + e1;
        a0 += e0 * (float)v0[0] + e1 * (float)v1[0];
        a1 += e0 * (float)v0[1] + e1 * (float)v1[1];
    }
    // 1-edge tail
    for (; j < e; j += 4) {
        int s0 = (int)(sd_csr[j] & 0xffffu);
        float x0 = as2[s0] + adn;
        f16x2 v0 = *(const f16x2*)(gp + (size_t)s0 * 32);
        x0 = fmaxf(x0, 0.2f * x0);
        float e0 = __expf(x0);
        sum += e0;
        a0 += e0 * (float)v0[0];
        a1 += e0 * (float)v0[1];
    }
#pragma unroll
    for (int d = 16; d < 64; d <<= 1) {
        sum += __shfl_xor(sum, d);
        a0 += __shfl_xor(a0, d);
        a1 += __shfl_xor(a1, d);
    }
    if (slot == 0) {
        float inv = 1.f / (sum + 1e-16f);
        float2 o;
        o.x = a0 * inv + b2[2 * cp];
        o.y = a1 * inv + b2[2 * cp + 1];
        *(float2*)(out + (size_t)n * 32 + 2 * cp) = o;
    }
}

// ---------------- launch ----------------

extern "C" void kernel_launch(void* const* d_in, const int* in_sizes, int n_in,
                              void* d_out, int out_size, void* d_ws, size_t ws_size,
                              hipStream_t stream) {
    const float* x    = (const float*)d_in[0];
    const int*   ei   = (const int*)d_in[1];
    const float* W1   = (const float*)d_in[2];
    const float* As1  = (const float*)d_in[3];
    const float* Ad1  = (const float*)d_in[4];
    const float* b1   = (const float*)d_in[5];
    const float* W2   = (const float*)d_in[6];
    const float* As2  = (const float*)d_in[7];
    const float* Ad2  = (const float*)d_in[8];
    const float* b2   = (const float*)d_in[9];
    float* out = (float*)d_out;

    char* p = (char*)d_ws;
    auto alloc = [&](size_t bytes) -> char* {
        char* r = p;
        p += (bytes + 255) & ~(size_t)255;
        return r;
    };
    f16* h1h      = (f16*)alloc((size_t)NNODES * 256 * 2);
    f16* h2h      = (f16*)alloc((size_t)NNODES * 256 * 2);
    f16* W1f      = (f16*)alloc((size_t)128 * 256 * 2);
    f16* W2f      = (f16*)alloc((size_t)256 * 32 * 2);
    f16* gh       = (f16*)alloc((size_t)NNODES * 32 * 2);
    float* asrc1  = (float*)alloc((size_t)NNODES * 8 * 4);
    float* adst1  = (float*)alloc((size_t)NNODES * 8 * 4);
    float* asrc2  = (float*)alloc((size_t)NNODES * 4);
    float* adst2  = (float*)alloc((size_t)NNODES * 4);
    int* deg      = (int*)alloc((size_t)NNODES * 4);
    int* incl     = (int*)alloc((size_t)NNODES * 4);
    int* rowst    = (int*)alloc((size_t)(NNODES + 1) * 4);
    int* rank     = (int*)alloc((size_t)NEDGES * 4);
    unsigned* sdc = (unsigned*)alloc((size_t)NEDGES * 4);
    int* partial  = (int*)alloc(256 * 4);

    const int EB = NEDGES / 256;           // 3125
    const int NCH = (NNODES + 255) / 256;  // 196

    hipMemsetAsync(deg, 0, (size_t)NNODES * 4, stream);
    k_deg_wfrag<<<EB + 160, 256, 0, stream>>>(ei, deg, rank, W1, W2, W1f, W2f);
    k_scanA<<<NCH, 256, 0, stream>>>(deg, incl, partial);
    k_scanC<<<NCH, 256, 0, stream>>>(deg, incl, partial, rowst);

    k_gemm1_sc<<<GB + EB, 256, 0, stream>>>(x, W1f, As1, Ad1, h1h, asrc1, adst1, ei, rowst, rank, sdc);
    k_agg1<<<NNODES / 4, 256, 0, stream>>>(rowst, sdc, asrc1, adst1, h1h, b1, h2h);

    k_gemm2<<<(NNODES + 63) / 64, 256, 0, stream>>>(h2h, W2f, As2, Ad2, gh, asrc2, adst2);
    k_agg2<<<NNODES / 4, 256, 0, stream>>>(rowst, sdc, asrc2, adst2, gh, b2, out);
}

// Round 3
// 254.183 us; speedup vs baseline: 1.1737x; 1.0459x over previous
//
#include <hip/hip_runtime.h>
#include <math.h>

#define NNODES 50000
#define NEDGES 800000
#define GB 782  // gemm1 row-blocks = (NNODES+63)/64

typedef _Float16 f16;
typedef _Float16 f16x8 __attribute__((ext_vector_type(8)));
typedef _Float16 f16x4 __attribute__((ext_vector_type(4)));
typedef _Float16 f16x2 __attribute__((ext_vector_type(2)));
typedef float f32x4 __attribute__((ext_vector_type(4)));
typedef float f32x8 __attribute__((ext_vector_type(8)));
typedef unsigned short u16;

// ---------------- CSR build + weight pack ----------------

// blocks [0,3125): degree histogram + per-edge rank (atomic return value);
// blocks [3125,3285): weight fragment pack
__global__ __launch_bounds__(256) void k_deg_wfrag(const int* __restrict__ ei, int* __restrict__ deg,
                                                   int* __restrict__ rank,
                                                   const float* __restrict__ W1, const float* __restrict__ W2,
                                                   f16* __restrict__ W1f, f16* __restrict__ W2f) {
    int bid = blockIdx.x;
    if (bid < NEDGES / 256) {
        int e = bid * 256 + threadIdx.x;
        rank[e] = atomicAdd(&deg[ei[NEDGES + e]], 1);
    } else {
        int id = (bid - NEDGES / 256) * 256 + threadIdx.x;
        if (id < 32768) {  // W1: 128 x 256
            int k = id >> 8, c = id & 255;
            int kc = k >> 5, quad = (k & 31) >> 3, j = k & 7;
            W1f[(((kc << 8) + c) * 4 + quad) * 8 + j] = (f16)W1[id];
        } else {           // W2: 256 x 32
            int i2 = id - 32768;
            int k = i2 >> 5, c = i2 & 31;
            int kc = k >> 5, quad = (k & 31) >> 3, j = k & 7;
            W2f[(((kc << 5) + c) * 4 + quad) * 8 + j] = (f16)W2[i2];
        }
    }
}

__global__ __launch_bounds__(256) void k_scanA(const int* __restrict__ deg, int* __restrict__ incl,
                                               int* __restrict__ partial) {
    int t = threadIdx.x;
    int i = blockIdx.x * 256 + t;
    int v = (i < NNODES) ? deg[i] : 0;
    int lane = t & 63, wid = t >> 6;
    int s = v;
#pragma unroll
    for (int d = 1; d < 64; d <<= 1) { int u = __shfl_up(s, d, 64); if (lane >= d) s += u; }
    __shared__ int wtot[4];
    if (lane == 63) wtot[wid] = s;
    __syncthreads();
    int off = 0;
    for (int w = 0; w < wid; ++w) off += wtot[w];
    s += off;
    if (i < NNODES) incl[i] = s;
    if (t == 255) partial[blockIdx.x] = s;
}

__global__ __launch_bounds__(256) void k_scanC(const int* __restrict__ deg, const int* __restrict__ incl,
                                               const int* __restrict__ partial, int* __restrict__ rowst) {
    int t = threadIdx.x, bid = blockIdx.x;
    int v = (t < bid) ? partial[t] : 0;  // bid <= 195 < 256
    int lane = t & 63, wid = t >> 6;
#pragma unroll
    for (int d = 1; d < 64; d <<= 1) v += __shfl_xor(v, d);
    __shared__ int ws[4];
    if (lane == 0) ws[wid] = v;
    __syncthreads();
    int choff = ws[0] + ws[1] + ws[2] + ws[3];
    int i = bid * 256 + t;
    if (i < NNODES) {
        int rs1 = incl[i] + choff;
        rowst[i + 1] = rs1;
        if (i == 0) rowst[0] = 0;
    }
}

// ---------------- gemm1 + atomic-free thin scatter (merged grid) ----------------
// mfma_f32_16x16x32_f16 (lane=tid&63, r=lane&15, quad=lane>>4):
//   A frag a[j]=A[r][quad*8+j]  B frag b[j]=B[quad*8+j][r]  D d[i]=D[quad*4+i][r]
// R2->R3 restructure: wave-per-64-col strip. Each wave preloads its B slice
// (16 x f16x8 = 64 VGPR) ONCE into registers (overlapped with X->LDS staging),
// then runs 64 register-resident MFMAs over all 64 rows. Global W1f traffic
// drops 4x (64 -> 16 loads/thread) and leaves the critical path. Each 64-col
// strip = exactly heads {2w, 2w+1}, so fused alpha stays wave-local.
// Blocks [GB,GB+3125): scatter sd16[rowst[d]+rank[e]] = s as u16 (consumers
// only use src; d<<16 was dead data) — halves scatter bytes + CSR read traffic.

__global__ __launch_bounds__(256) void k_gemm1_sc(const float* __restrict__ X, const f16* __restrict__ W1f,
                                                  const float* __restrict__ Asrc, const float* __restrict__ Adst,
                                                  f16* __restrict__ h1h, float* __restrict__ as1,
                                                  float* __restrict__ ad1, const int* __restrict__ ei,
                                                  const int* __restrict__ rowst, const int* __restrict__ rank,
                                                  u16* __restrict__ sd16) {
    __shared__ f16 sA[64 * 136];
    int bid = blockIdx.x;
    int t = threadIdx.x;
    if (bid >= GB) {  // scatter path (uniform per block)
        int e = (bid - GB) * 256 + t;
        if (e < NEDGES) {
            int s = ei[e], d = ei[NEDGES + e];
            int pos = rowst[d] + rank[e];
            sd16[pos] = (u16)s;
        }
        return;
    }
    int bm = bid * 64;
    int lane = t & 63, w = t >> 6;
    int r = lane & 15, quad = lane >> 4;
    int cw = w * 64;  // this wave's column strip
    // preload B slice into registers (issued before staging sync; L2-resident)
    f16x8 bf[4][4];
#pragma unroll
    for (int kc = 0; kc < 4; ++kc)
#pragma unroll
        for (int nt = 0; nt < 4; ++nt)
            bf[kc][nt] = *(const f16x8*)&W1f[(((kc << 8) + cw + nt * 16 + r) * 4 + quad) * 8];
    // stage X tile (64 rows x 128 cols) as f16
#pragma unroll
    for (int i = 0; i < 8; ++i) {
        int idx = i * 256 + t;
        int row = idx >> 5, c4 = (idx & 31) << 2;
        int gr = bm + row;
        float4 v = make_float4(0.f, 0.f, 0.f, 0.f);
        if (gr < NNODES) v = *(const float4*)(X + (size_t)gr * 128 + c4);
        f16x4 h = {(f16)v.x, (f16)v.y, (f16)v.z, (f16)v.w};
        *(f16x4*)&sA[row * 136 + c4] = h;
    }
    __syncthreads();
    f32x4 acc[4][4];  // [row-group rg][nt]
#pragma unroll
    for (int rg = 0; rg < 4; ++rg)
#pragma unroll
        for (int nt = 0; nt < 4; ++nt) acc[rg][nt] = (f32x4){0.f, 0.f, 0.f, 0.f};
#pragma unroll
    for (int kc = 0; kc < 4; ++kc)
#pragma unroll
        for (int rg = 0; rg < 4; ++rg) {
            f16x8 a = *(f16x8*)&sA[(rg * 16 + r) * 136 + kc * 32 + quad * 8];
#pragma unroll
            for (int nt = 0; nt < 4; ++nt)
                acc[rg][nt] = __builtin_amdgcn_mfma_f32_16x16x32_f16(a, bf[kc][nt], acc[rg][nt], 0, 0, 0);
        }
    // store h1h strip
#pragma unroll
    for (int rg = 0; rg < 4; ++rg)
#pragma unroll
        for (int nt = 0; nt < 4; ++nt)
#pragma unroll
            for (int i = 0; i < 4; ++i) {
                int gr = bm + rg * 16 + quad * 4 + i;
                if (gr < NNODES) h1h[(size_t)gr * 256 + cw + nt * 16 + r] = (f16)acc[rg][nt][i];
            }
    // fused alpha for this wave's 2 heads (head = 2w + hh), all 64 rows
    float asv[4], adv[4];
#pragma unroll
    for (int nt = 0; nt < 4; ++nt) {
        asv[nt] = Asrc[cw + nt * 16 + r];
        adv[nt] = Adst[cw + nt * 16 + r];
    }
#pragma unroll
    for (int rg = 0; rg < 4; ++rg)
#pragma unroll
        for (int i = 0; i < 4; ++i) {
            int gr = bm + rg * 16 + quad * 4 + i;
#pragma unroll
            for (int hh = 0; hh < 2; ++hh) {
                float ps = acc[rg][2 * hh][i] * asv[2 * hh] + acc[rg][2 * hh + 1][i] * asv[2 * hh + 1];
                float pd = acc[rg][2 * hh][i] * adv[2 * hh] + acc[rg][2 * hh + 1][i] * adv[2 * hh + 1];
#pragma unroll
                for (int off = 1; off < 16; off <<= 1) {
                    ps += __shfl_xor(ps, off);
                    pd += __shfl_xor(pd, off);
                }
                if (r == 0 && gr < NNODES) {
                    as1[(size_t)gr * 8 + 2 * w + hh] = ps;
                    ad1[(size_t)gr * 8 + 2 * w + hh] = pd;
                }
            }
        }
}

// gh[N,32](f16) = h2h @ W2; 64 rows per block; no LDS. Fused: layer-2 alpha dots.
__global__ __launch_bounds__(256) void k_gemm2(const f16* __restrict__ h2h, const f16* __restrict__ W2f,
                                               const float* __restrict__ Asrc, const float* __restrict__ Adst,
                                               f16* __restrict__ gh, float* __restrict__ as2,
                                               float* __restrict__ ad2) {
    int t = threadIdx.x;
    int bm = blockIdx.x * 64;
    int lane = t & 63, w = t >> 6;
    int r = lane & 15, quad = lane >> 4;
    int r0 = w * 16;
    int gra = bm + r0 + r;
    int grac = gra < NNODES ? gra : 0;
    f32x4 acc[2];
    acc[0] = (f32x4){0.f, 0.f, 0.f, 0.f};
    acc[1] = (f32x4){0.f, 0.f, 0.f, 0.f};
#pragma unroll
    for (int kc = 0; kc < 8; ++kc) {
        f16x8 a = *(const f16x8*)(h2h + (size_t)grac * 256 + kc * 32 + quad * 8);
#pragma unroll
        for (int nt = 0; nt < 2; ++nt) {
            f16x8 b = *(const f16x8*)&W2f[(((kc << 5) + nt * 16 + r) * 4 + quad) * 8];
            acc[nt] = __builtin_amdgcn_mfma_f32_16x16x32_f16(a, b, acc[nt], 0, 0, 0);
        }
    }
#pragma unroll
    for (int nt = 0; nt < 2; ++nt)
#pragma unroll
        for (int i = 0; i < 4; ++i) {
            int gr = bm + r0 + quad * 4 + i;
            if (gr < NNODES) gh[(size_t)gr * 32 + nt * 16 + r] = (f16)acc[nt][i];
        }
    float as0 = Asrc[r], as16 = Asrc[16 + r];
    float ad0 = Adst[r], ad16 = Adst[16 + r];
#pragma unroll
    for (int i = 0; i < 4; ++i) {
        int gr = bm + r0 + quad * 4 + i;
        float ps = acc[0][i] * as0 + acc[1][i] * as16;
        float pd = acc[0][i] * ad0 + acc[1][i] * ad16;
#pragma unroll
        for (int off = 1; off < 16; off <<= 1) {
            ps += __shfl_xor(ps, off);
            pd += __shfl_xor(pd, off);
        }
        if (r == 0 && gr < NNODES) { as2[gr] = ps; ad2[gr] = pd; }
    }
}

// ---------------- fused softmax + aggregate ----------------
// No max-subtraction: logits O(1) by construction (validated R6-R15).
// Single pass; 8-edge unroll per slot (R2). CSR index array is u16 (R3).

// Wave-per-node, 4 nodes/block. lane = slot(2) x ch32; each lane covers 8 channels
// (f16x8 gather, 16 B/lane) of head hm = ch32>>2; alpha recomputed per edge from
// L2-resident as1 (1.6 MB).
__global__ __launch_bounds__(256) void k_agg1(const int* __restrict__ rowst, const u16* __restrict__ sd16,
                                              const float* __restrict__ as1, const float* __restrict__ ad1,
                                              const f16* __restrict__ h1h, const float* __restrict__ b1,
                                              f16* __restrict__ h2h) {
    int w = threadIdx.x >> 6, lane = threadIdx.x & 63;
    int n = blockIdx.x * 4 + w;
    int s = rowst[n], e = rowst[n + 1];
    int slot = lane >> 5;
    int ch32 = lane & 31;
    int c0 = ch32 << 3;
    int hm = ch32 >> 2;
    float adn = ad1[(size_t)n * 8 + hm];
    const f16* __restrict__ hp = h1h + c0;
    const float* __restrict__ ap = as1 + hm;
    f32x8 acc = (f32x8){0.f, 0.f, 0.f, 0.f, 0.f, 0.f, 0.f, 0.f};
    float sum = 0.f;
    int j = s + slot;
    // 8-edge unroll: 8 index loads, 8 alpha gathers, 8 f16x8 row gathers in flight
    for (; j + 14 < e; j += 16) {
        int si[8];
#pragma unroll
        for (int u = 0; u < 8; ++u) si[u] = (int)sd16[j + 2 * u];
        float xv[8];
#pragma unroll
        for (int u = 0; u < 8; ++u) xv[u] = ap[(size_t)si[u] * 8];
        f16x8 vv[8];
#pragma unroll
        for (int u = 0; u < 8; ++u) vv[u] = *(const f16x8*)(hp + (size_t)si[u] * 256);
#pragma unroll
        for (int u = 0; u < 8; ++u) {
            float x = xv[u] + adn;
            x = fmaxf(x, 0.2f * x);
            float ee = __expf(x);
            sum += ee;
#pragma unroll
            for (int k = 0; k < 8; ++k) acc[k] += ee * (float)vv[u][k];
        }
    }
    // 4-edge tail
    for (; j + 6 < e; j += 8) {
        int si[4];
#pragma unroll
        for (int u = 0; u < 4; ++u) si[u] = (int)sd16[j + 2 * u];
        float xv[4];
#pragma unroll
        for (int u = 0; u < 4; ++u) xv[u] = ap[(size_t)si[u] * 8];
        f16x8 vv[4];
#pragma unroll
        for (int u = 0; u < 4; ++u) vv[u] = *(const f16x8*)(hp + (size_t)si[u] * 256);
#pragma unroll
        for (int u = 0; u < 4; ++u) {
            float x = xv[u] + adn;
            x = fmaxf(x, 0.2f * x);
            float ee = __expf(x);
            sum += ee;
#pragma unroll
            for (int k = 0; k < 8; ++k) acc[k] += ee * (float)vv[u][k];
        }
    }
    // 1-edge tail
    for (; j < e; j += 2) {
        int s0 = (int)sd16[j];
        float x0 = ap[(size_t)s0 * 8] + adn;
        f16x8 v0 = *(const f16x8*)(hp + (size_t)s0 * 256);
        x0 = fmaxf(x0, 0.2f * x0);
        float e0 = __expf(x0);
        sum += e0;
#pragma unroll
        for (int k = 0; k < 8; ++k) acc[k] += e0 * (float)v0[k];
    }
    sum += __shfl_xor(sum, 32);
#pragma unroll
    for (int k = 0; k < 8; ++k) acc[k] += __shfl_xor(acc[k], 32);
    if (slot == 0) {
        float inv = 1.f / (sum + 1e-16f);
        float4 b0 = *(const float4*)(b1 + c0);
        float4 b4 = *(const float4*)(b1 + c0 + 4);
        float o[8] = {acc[0] * inv + b0.x, acc[1] * inv + b0.y, acc[2] * inv + b0.z, acc[3] * inv + b0.w,
                      acc[4] * inv + b4.x, acc[5] * inv + b4.y, acc[6] * inv + b4.z, acc[7] * inv + b4.w};
        f16x8 oh;
#pragma unroll
        for (int k = 0; k < 8; ++k) {
            float v = o[k];
            v = v > 0.f ? v : __expf(v) - 1.f;  // fused ELU
            oh[k] = (f16)v;
        }
        *(f16x8*)(h2h + (size_t)n * 256 + c0) = oh;
    }
}

// Wave-per-node, single pass; lane = slot(4) x chpair(16), f16x2 gathers of gh
// (3.2 MB, effectively L2-resident); alpha from L2-resident as2 (200 KB).
// 4-edge unroll per slot for MLP depth, then 2-edge, then 1-edge tails.
__global__ __launch_bounds__(256) void k_agg2(const int* __restrict__ rowst, const u16* __restrict__ sd16,
                                              const float* __restrict__ as2, const float* __restrict__ ad2,
                                              const f16* __restrict__ gh, const float* __restrict__ b2,
                                              float* __restrict__ out) {
    int w = threadIdx.x >> 6, lane = threadIdx.x & 63;
    int n = blockIdx.x * 4 + w;
    int s = rowst[n], e = rowst[n + 1];
    int slot = lane >> 4;
    int cp = lane & 15;  // channels 2cp, 2cp+1
    float adn = ad2[n];
    const f16* __restrict__ gp = gh + 2 * cp;
    float a0 = 0.f, a1 = 0.f, sum = 0.f;
    int j = s + slot;
    // 4-edge unroll
    for (; j + 12 < e; j += 16) {
        int si[4];
#pragma unroll
        for (int u = 0; u < 4; ++u) si[u] = (int)sd16[j + 4 * u];
        float xv[4];
#pragma unroll
        for (int u = 0; u < 4; ++u) xv[u] = as2[si[u]];
        f16x2 vv[4];
#pragma unroll
        for (int u = 0; u < 4; ++u) vv[u] = *(const f16x2*)(gp + (size_t)si[u] * 32);
#pragma unroll
        for (int u = 0; u < 4; ++u) {
            float x = xv[u] + adn;
            x = fmaxf(x, 0.2f * x);
            float ee = __expf(x);
            sum += ee;
            a0 += ee * (float)vv[u][0];
            a1 += ee * (float)vv[u][1];
        }
    }
    // 2-edge tail
    for (; j + 4 < e; j += 8) {
        int s0 = (int)sd16[j];
        int s1 = (int)sd16[j + 4];
        float x0 = as2[s0] + adn, x1 = as2[s1] + adn;
        f16x2 v0 = *(const f16x2*)(gp + (size_t)s0 * 32);
        f16x2 v1 = *(const f16x2*)(gp + (size_t)s1 * 32);
        x0 = fmaxf(x0, 0.2f * x0);
        x1 = fmaxf(x1, 0.2f * x1);
        float e0 = __expf(x0), e1 = __expf(x1);
        sum += e0 + e1;
        a0 += e0 * (float)v0[0] + e1 * (float)v1[0];
        a1 += e0 * (float)v0[1] + e1 * (float)v1[1];
    }
    // 1-edge tail
    for (; j < e; j += 4) {
        int s0 = (int)sd16[j];
        float x0 = as2[s0] + adn;
        f16x2 v0 = *(const f16x2*)(gp + (size_t)s0 * 32);
        x0 = fmaxf(x0, 0.2f * x0);
        float e0 = __expf(x0);
        sum += e0;
        a0 += e0 * (float)v0[0];
        a1 += e0 * (float)v0[1];
    }
#pragma unroll
    for (int d = 16; d < 64; d <<= 1) {
        sum += __shfl_xor(sum, d);
        a0 += __shfl_xor(a0, d);
        a1 += __shfl_xor(a1, d);
    }
    if (slot == 0) {
        float inv = 1.f / (sum + 1e-16f);
        float2 o;
        o.x = a0 * inv + b2[2 * cp];
        o.y = a1 * inv + b2[2 * cp + 1];
        *(float2*)(out + (size_t)n * 32 + 2 * cp) = o;
    }
}

// ---------------- launch ----------------

extern "C" void kernel_launch(void* const* d_in, const int* in_sizes, int n_in,
                              void* d_out, int out_size, void* d_ws, size_t ws_size,
                              hipStream_t stream) {
    const float* x    = (const float*)d_in[0];
    const int*   ei   = (const int*)d_in[1];
    const float* W1   = (const float*)d_in[2];
    const float* As1  = (const float*)d_in[3];
    const float* Ad1  = (const float*)d_in[4];
    const float* b1   = (const float*)d_in[5];
    const float* W2   = (const float*)d_in[6];
    const float* As2  = (const float*)d_in[7];
    const float* Ad2  = (const float*)d_in[8];
    const float* b2   = (const float*)d_in[9];
    float* out = (float*)d_out;

    char* p = (char*)d_ws;
    auto alloc = [&](size_t bytes) -> char* {
        char* r = p;
        p += (bytes + 255) & ~(size_t)255;
        return r;
    };
    f16* h1h      = (f16*)alloc((size_t)NNODES * 256 * 2);
    f16* h2h      = (f16*)alloc((size_t)NNODES * 256 * 2);
    f16* W1f      = (f16*)alloc((size_t)128 * 256 * 2);
    f16* W2f      = (f16*)alloc((size_t)256 * 32 * 2);
    f16* gh       = (f16*)alloc((size_t)NNODES * 32 * 2);
    float* asrc1  = (float*)alloc((size_t)NNODES * 8 * 4);
    float* adst1  = (float*)alloc((size_t)NNODES * 8 * 4);
    float* asrc2  = (float*)alloc((size_t)NNODES * 4);
    float* adst2  = (float*)alloc((size_t)NNODES * 4);
    int* deg      = (int*)alloc((size_t)NNODES * 4);
    int* incl     = (int*)alloc((size_t)NNODES * 4);
    int* rowst    = (int*)alloc((size_t)(NNODES + 1) * 4);
    int* rank     = (int*)alloc((size_t)NEDGES * 4);
    u16* sdc      = (u16*)alloc((size_t)NEDGES * 2);
    int* partial  = (int*)alloc(256 * 4);

    const int EB = NEDGES / 256;           // 3125
    const int NCH = (NNODES + 255) / 256;  // 196

    hipMemsetAsync(deg, 0, (size_t)NNODES * 4, stream);
    k_deg_wfrag<<<EB + 160, 256, 0, stream>>>(ei, deg, rank, W1, W2, W1f, W2f);
    k_scanA<<<NCH, 256, 0, stream>>>(deg, incl, partial);
    k_scanC<<<NCH, 256, 0, stream>>>(deg, incl, partial, rowst);

    k_gemm1_sc<<<GB + EB, 256, 0, stream>>>(x, W1f, As1, Ad1, h1h, asrc1, adst1, ei, rowst, rank, sdc);
    k_agg1<<<NNODES / 4, 256, 0, stream>>>(rowst, sdc, asrc1, adst1, h1h, b1, h2h);

    k_gemm2<<<(NNODES + 63) / 64, 256, 0, stream>>>(h2h, W2f, As2, Ad2, gh, asrc2, adst2);
    k_agg2<<<NNODES / 4, 256, 0, stream>>>(rowst, sdc, asrc2, adst2, gh, b2, out);
}